// Round 1
// baseline (1512.555 us; speedup 1.0000x reference)
//
#include <hip/hip_runtime.h>
#include <math.h>

// ---------------------------------------------------------------------------
// GroundingModule: f32 reference-faithful implementation (round 0, correctness)
//   BS=2048, L=32, D=768, KS=5
// Pipeline:
//   K0 rowstats(v), rowstats(qa)           -> per-row (s=rstd, t=-mean*rstd)
//   K1 gemm_fused: out = gelu( ((X*s+t)*g + lnb) @ W + bias )   (LN fused in A)
//   K2 gatestats: gate=tanh(v_p . qa_p), stats of v_p row -> (s,t) for LN(v_p*gate)
//   K3 gemm_fused: h2 = gelu(LN2 @ g_w1 + g_b1)
//   K4 logits: h2 . g_w2 + g_b2
//   K5 head: softmax -> gaussian smooth -> softmax -> argmax/window decode, writes
//            all 6 outputs (flat f32, return order)
// ---------------------------------------------------------------------------

#define DEV __device__ __forceinline__

constexpr int KDIM = 768;
constexpr int BK   = 16;

// output offsets (floats) in return order
constexpr int OFF_KG   = 0;              // key_gs   [2048,32]
constexpr int OFF_MI   = 65536;          // max_indices [2048,2]
constexpr int OFF_ST   = 69632;          // start_time [2048]
constexpr int OFF_ET   = 71680;          // end_time [2048]
constexpr int OFF_MASK = 73728;          // mask [2048,32]
constexpr int OFF_ORI  = 139264;         // ori_key [2048,32]

DEV float gelu_erf(float x) { return 0.5f * x * (1.0f + erff(x * 0.70710678118654752f)); }

DEV float wave_sum(float v) { for (int o = 32; o; o >>= 1) v += __shfl_xor(v, o); return v; }
DEV float wave_max(float v) { for (int o = 32; o; o >>= 1) v = fmaxf(v, __shfl_xor(v, o)); return v; }

// ---------------------------------------------------------------------------
// K0: per-row mean/rstd -> (s, t) with s=rstd, t=-mean*rstd. One wave per row.
__global__ __launch_bounds__(256)
void rowstats(const float* __restrict__ X, float2* __restrict__ st, int M)
{
    int wave = threadIdx.x >> 6, lane = threadIdx.x & 63;
    int row = blockIdx.x * 4 + wave;
    if (row >= M) return;
    const float4* xr = reinterpret_cast<const float4*>(X + (size_t)row * KDIM);
    float s = 0.f, ss = 0.f;
#pragma unroll
    for (int i = 0; i < 3; ++i) {
        float4 v = xr[lane + i * 64];
        s  += v.x + v.y + v.z + v.w;
        ss += v.x * v.x + v.y * v.y + v.z * v.z + v.w * v.w;
    }
    s = wave_sum(s); ss = wave_sum(ss);
    if (lane == 0) {
        float m = s * (1.0f / 768.0f);
        float var = ss * (1.0f / 768.0f) - m * m;
        float rstd = rsqrtf(var + 1e-5f);
        st[row] = make_float2(rstd, -m * rstd);
    }
}

// ---------------------------------------------------------------------------
// K2: gate = tanh(v_p[row,:] . qa_p[b,:]); stats of v_p row; emit (s,t) for
//     LN(v_p*gate): s = gate*den, t = -gate*m*den, den = rsqrt(gate^2*var+eps)
__global__ __launch_bounds__(256)
void gatestats(const float* __restrict__ vp, const float* __restrict__ qap,
               float2* __restrict__ st2)
{
    int wave = threadIdx.x >> 6, lane = threadIdx.x & 63;
    int row = blockIdx.x * 4 + wave;          // row = b*32 + l, rows = 65536
    int b = row >> 5;
    const float4* xr = reinterpret_cast<const float4*>(vp + (size_t)row * KDIM);
    const float4* qr = reinterpret_cast<const float4*>(qap + (size_t)b * KDIM);
    float s = 0.f, ss = 0.f, d = 0.f;
#pragma unroll
    for (int i = 0; i < 3; ++i) {
        float4 v = xr[lane + i * 64];
        float4 q = qr[lane + i * 64];
        s  += v.x + v.y + v.z + v.w;
        ss += v.x * v.x + v.y * v.y + v.z * v.z + v.w * v.w;
        d  += v.x * q.x + v.y * q.y + v.z * q.z + v.w * q.w;
    }
    s = wave_sum(s); ss = wave_sum(ss); d = wave_sum(d);
    if (lane == 0) {
        float gate = tanhf(d);
        float m = s * (1.0f / 768.0f);
        float var = ss * (1.0f / 768.0f) - m * m;
        float den = rsqrtf(gate * gate * var + 1e-5f);
        st2[row] = make_float2(gate * den, -gate * m * den);
    }
}

// ---------------------------------------------------------------------------
// K1/K3: C[M,N] = gelu( A @ W + bias ), A[r,k] = (X[r,k]*s_r + t_r)*g[k] + lnb[k]
template<int BM, int BN, int TM, int TN>
__global__ __launch_bounds__(256)
void gemm_fused(const float* __restrict__ X, const float2* __restrict__ st,
                const float* __restrict__ gw, const float* __restrict__ gb,
                const float* __restrict__ W, const float* __restrict__ bias,
                float* __restrict__ out, int M, int N)
{
    static_assert((BM / TM) * (BN / TN) == 256, "256 threads");
    __shared__ float As[BK][BM];   // transposed: As[k][m]
    __shared__ float Bs[BK][BN];
    const int t = threadIdx.x;
    constexpr int TXN = BN / TN;
    const int tx = t % TXN;
    const int ty = t / TXN;
    const int row0 = blockIdx.y * BM;
    const int col0 = blockIdx.x * BN;

    float acc[TM][TN] = {};

    constexpr int A_IT = BM * BK / 4 / 256;
    constexpr int B_IT = BK * BN / 4 / 256;

    for (int k0 = 0; k0 < KDIM; k0 += BK) {
#pragma unroll
        for (int i = 0; i < A_IT; ++i) {
            int idx = t + i * 256;
            int r = idx >> 2;            // BK/4 == 4 float4 per row
            int c = (idx & 3) << 2;
            float4 xv = *reinterpret_cast<const float4*>(X + (size_t)(row0 + r) * KDIM + k0 + c);
            float2 s = st[row0 + r];
            float4 gv = *reinterpret_cast<const float4*>(gw + k0 + c);
            float4 bv = *reinterpret_cast<const float4*>(gb + k0 + c);
            As[c + 0][r] = fmaf(fmaf(xv.x, s.x, s.y), gv.x, bv.x);
            As[c + 1][r] = fmaf(fmaf(xv.y, s.x, s.y), gv.y, bv.y);
            As[c + 2][r] = fmaf(fmaf(xv.z, s.x, s.y), gv.z, bv.z);
            As[c + 3][r] = fmaf(fmaf(xv.w, s.x, s.y), gv.w, bv.w);
        }
#pragma unroll
        for (int i = 0; i < B_IT; ++i) {
            int idx = t + i * 256;
            int r = idx / (BN / 4);
            int c = (idx % (BN / 4)) << 2;
            *reinterpret_cast<float4*>(&Bs[r][c]) =
                *reinterpret_cast<const float4*>(W + (size_t)(k0 + r) * N + col0 + c);
        }
        __syncthreads();
#pragma unroll
        for (int kk = 0; kk < BK; ++kk) {
            float a[TM], b[TN];
#pragma unroll
            for (int i = 0; i < TM; i += 4)
                *reinterpret_cast<float4*>(&a[i]) = *reinterpret_cast<const float4*>(&As[kk][ty * TM + i]);
#pragma unroll
            for (int j = 0; j < TN; j += 4)
                *reinterpret_cast<float4*>(&b[j]) = *reinterpret_cast<const float4*>(&Bs[kk][tx * TN + j]);
#pragma unroll
            for (int i = 0; i < TM; ++i)
#pragma unroll
                for (int j = 0; j < TN; ++j)
                    acc[i][j] = fmaf(a[i], b[j], acc[i][j]);
        }
        __syncthreads();
    }
#pragma unroll
    for (int i = 0; i < TM; ++i) {
        size_t row = row0 + ty * TM + i;
#pragma unroll
        for (int j = 0; j < TN; j += 4) {
            int col = col0 + tx * TN + j;
            float4 o;
            o.x = gelu_erf(acc[i][j + 0] + bias[col + 0]);
            o.y = gelu_erf(acc[i][j + 1] + bias[col + 1]);
            o.z = gelu_erf(acc[i][j + 2] + bias[col + 2]);
            o.w = gelu_erf(acc[i][j + 3] + bias[col + 3]);
            *reinterpret_cast<float4*>(out + row * N + col) = o;
        }
    }
}

// ---------------------------------------------------------------------------
// K4: logits[row] = h2[row,:384] . w2 + b2. One wave per row.
__global__ __launch_bounds__(256)
void logits_kernel(const float* __restrict__ h2, const float* __restrict__ w2,
                   const float* __restrict__ b2, float* __restrict__ lg)
{
    int wave = threadIdx.x >> 6, lane = threadIdx.x & 63;
    int row = blockIdx.x * 4 + wave;
    const float2* hr = reinterpret_cast<const float2*>(h2 + (size_t)row * 384);
    const float2* wr = reinterpret_cast<const float2*>(w2);
    float d = 0.f;
#pragma unroll
    for (int i = 0; i < 3; ++i) {
        float2 h = hr[lane + i * 64];
        float2 w = wr[lane + i * 64];
        d += h.x * w.x + h.y * w.y;
    }
    d = wave_sum(d);
    if (lane == 0) lg[row] = d + b2[0];
}

// ---------------------------------------------------------------------------
// K5: per-batch decode. One wave (64 threads) per batch; lanes 0..31 = frames.
__global__ __launch_bounds__(64)
void head_kernel(const float* __restrict__ lg, const float* __restrict__ sigma_p,
                 float* __restrict__ out)
{
    int b = blockIdx.x, lane = threadIdx.x;
    __shared__ float ok[36];     // zero-padded ori_key: ok[2..33] = ori[0..31]
    __shared__ float kg[32];
    __shared__ int sel[2];

    if (lane < 36) ok[lane] = 0.f;
    __syncthreads();

    // softmax(logits) over 32 frames -> ori_key
    float x = (lane < 32) ? lg[b * 32 + lane] : -3.4e38f;
    float mx = wave_max(x);
    float e = (lane < 32) ? expf(x - mx) : 0.f;
    float sum = wave_sum(e);
    float ori = e / sum;
    if (lane < 32) {
        out[OFF_ORI + b * 32 + lane] = ori;
        ok[lane + 2] = ori;
    }
    __syncthreads();

    // gaussian 5-tap smoothing (kernel from sigma, normalized)
    float sg = sigma_p[0];
    float kern[5]; float ks = 0.f;
#pragma unroll
    for (int k = 0; k < 5; ++k) { float xx = (float)(k - 2) / sg; kern[k] = expf(-0.5f * xx * xx); ks += kern[k]; }
    float sm = -3.4e38f;
    if (lane < 32) {
        sm = 0.f;
#pragma unroll
        for (int k = 0; k < 5; ++k) sm += (kern[k] / ks) * ok[lane + k];
    }
    // softmax(smoothed) -> key_gs
    float mx2 = wave_max(sm);
    float e2 = (lane < 32) ? expf(sm - mx2) : 0.f;
    float sum2 = wave_sum(e2);
    float kgv = e2 / sum2;
    if (lane < 32) {
        out[OFF_KG + b * 32 + lane] = kgv;
        kg[lane] = kgv;
    }
    __syncthreads();

    if (lane == 0) {
        // first argmax
        int pm = 0; float bv = kg[0];
        for (int i = 1; i < 32; ++i) if (kg[i] > bv) { bv = kg[i]; pm = i; }
        // sequential cumsum (matches np)
        float cum[33]; cum[0] = 0.f;
        for (int i = 0; i < 32; ++i) cum[i + 1] = cum[i] + kg[i];
        // windows of size 1,3,5 containing pm; first max in (w, s) order wins
        float bs = -3.4e38f; int bst = 0, ben = 0;
        const int wsz[3] = {1, 3, 5};
        for (int wi = 0; wi < 3; ++wi) {
            int w = wsz[wi];
            for (int s = 0; s + w <= 32; ++s) {
                if (pm >= s && pm < s + w) {
                    float sc = cum[s + w] - cum[s];
                    if (sc > bs) { bs = sc; bst = s; ben = s + w; }
                }
            }
        }
        out[OFF_MI + b * 2 + 0] = (float)bst;
        out[OFF_MI + b * 2 + 1] = (float)ben;
        out[OFF_ST + b] = (float)bst / 31.0f;
        out[OFF_ET + b] = (float)ben / 31.0f;
        sel[0] = bst; sel[1] = ben;
    }
    __syncthreads();
    if (lane < 32)
        out[OFF_MASK + b * 32 + lane] = (lane >= sel[0] && lane <= sel[1]) ? 1.0f : 0.0f;
}

// ---------------------------------------------------------------------------
extern "C" void kernel_launch(void* const* d_in, const int* in_sizes, int n_in,
                              void* d_out, int out_size, void* d_ws, size_t ws_size,
                              hipStream_t stream)
{
    const float* v      = (const float*)d_in[0];
    const float* qa     = (const float*)d_in[1];
    const float* vp_lng = (const float*)d_in[2];
    const float* vp_lnb = (const float*)d_in[3];
    const float* vp_w   = (const float*)d_in[4];
    const float* vp_b   = (const float*)d_in[5];
    const float* qp_lng = (const float*)d_in[6];
    const float* qp_lnb = (const float*)d_in[7];
    const float* qp_w   = (const float*)d_in[8];
    const float* qp_b   = (const float*)d_in[9];
    const float* g_lng  = (const float*)d_in[10];
    const float* g_lnb  = (const float*)d_in[11];
    const float* g_w1   = (const float*)d_in[12];
    const float* g_b1   = (const float*)d_in[13];
    const float* g_w2   = (const float*)d_in[14];
    const float* g_b2   = (const float*)d_in[15];
    const float* sigma  = (const float*)d_in[16];
    float* outf = (float*)d_out;

    // workspace layout (floats); total ~77.4M floats = ~310 MB
    float* ws    = (float*)d_ws;
    float* v_p   = ws;                       // 65536*768 = 50331648
    float* st_v  = v_p + 50331648;           // 65536*2   = 131072
    float* st_qa = st_v + 131072;            // 2048*2    = 4096
    float* qa_p  = st_qa + 4096;             // 2048*768  = 1572864
    float* st2   = qa_p + 1572864;           // 65536*2   = 131072
    float* h2    = st2 + 131072;             // 65536*384 = 25165824
    float* lgts  = h2 + 25165824;            // 65536

    rowstats<<<16384, 256, 0, stream>>>(v, (float2*)st_v, 65536);
    rowstats<<<512, 256, 0, stream>>>(qa, (float2*)st_qa, 2048);

    // qa_p = gelu(LN(qa) @ qp_w + qp_b)   [2048,768]
    gemm_fused<64, 64, 4, 4><<<dim3(12, 32), 256, 0, stream>>>(
        qa, (const float2*)st_qa, qp_lng, qp_lnb, qp_w, qp_b, qa_p, 2048, 768);

    // v_p = gelu(LN(v) @ vp_w + vp_b)     [65536,768]
    gemm_fused<128, 128, 8, 8><<<dim3(6, 512), 256, 0, stream>>>(
        v, (const float2*)st_v, vp_lng, vp_lnb, vp_w, vp_b, v_p, 65536, 768);

    // gate + LN2 stats
    gatestats<<<16384, 256, 0, stream>>>(v_p, qa_p, (float2*)st2);

    // h2 = gelu(LN2(v_p*gate) @ g_w1 + g_b1)   [65536,384]
    gemm_fused<128, 128, 8, 8><<<dim3(3, 512), 256, 0, stream>>>(
        v_p, (const float2*)st2, g_lng, g_lnb, g_w1, g_b1, h2, 65536, 384);

    logits_kernel<<<16384, 256, 0, stream>>>(h2, g_w2, g_b2, lgts);

    head_kernel<<<2048, 64, 0, stream>>>(lgts, sigma, outf);
}

// Round 2
// 768.808 us; speedup vs baseline: 1.9674x; 1.9674x over previous
//
#include <hip/hip_runtime.h>
#include <math.h>
#include <stdint.h>

// ---------------------------------------------------------------------------
// GroundingModule — round 1: split-bf16 (3-MFMA) matrix-core GEMMs.
//   BS=2048, L=32, D=768, KS=5.  All f32 I/O; internal GEMMs in hi/lo bf16.
// Pipeline per chunk (M chunked 2x32768 to fit workspace):
//   prep_A1 : rowstats+LN+split  v -> A1h/A1l              (fused, 1 pass)
//   gemm<768,VP>   : v_p = gelu(A1 @ vp_w^T + vp_b) -> vph/vpl (bf16 hi/lo)
//   prep_A2 : gate=tanh(vp.qa_p), LN2(vp*gate)+split -> A1h/A1l (reuse)
//   gemm<384,LOGIT>: h=gelu(A2 @ g_w1^T + g_b1); partial row-dot with g_w2
// head_kernel: logits=sum(partials)+b2 -> softmax -> smooth -> softmax ->
//              argmax/window decode -> all 6 outputs
// ---------------------------------------------------------------------------

#define DEV __device__ __forceinline__

typedef __attribute__((ext_vector_type(8))) short short8v;   // 8 bf16
typedef __attribute__((ext_vector_type(4))) float f32x4;

constexpr int KDIM  = 768;
constexpr int CHUNK = 32768;

// output offsets (floats) in return order
constexpr int OFF_KG   = 0;
constexpr int OFF_MI   = 65536;
constexpr int OFF_ST   = 69632;
constexpr int OFF_ET   = 71680;
constexpr int OFF_MASK = 73728;
constexpr int OFF_ORI  = 139264;

DEV float gelu_erf(float x) { return 0.5f * x * (1.0f + erff(x * 0.70710678118654752f)); }
DEV float wave_sum(float v) { for (int o = 32; o; o >>= 1) v += __shfl_xor(v, o); return v; }
DEV float wave_max(float v) { for (int o = 32; o; o >>= 1) v = fmaxf(v, __shfl_xor(v, o)); return v; }

DEV short f2bf(float x) {                       // f32 -> bf16 (RNE)
    uint32_t u = __builtin_bit_cast(uint32_t, x);
    u = u + 0x7fffu + ((u >> 16) & 1u);
    return (short)(u >> 16);
}
DEV float bf2f(short b) {
    uint32_t u = ((uint32_t)(uint16_t)b) << 16;
    return __builtin_bit_cast(float, u);
}

DEV void gl_lds16(const void* g, void* l) {     // async 16B/lane global->LDS
    __builtin_amdgcn_global_load_lds(
        (const __attribute__((address_space(1))) uint32_t*)g,
        (__attribute__((address_space(3))) uint32_t*)l, 16, 0, 0);
}

// ---------------------------------------------------------------------------
// prep_A1: fused rowstats + LN-affine + hi/lo split.  One wave per row.
__global__ __launch_bounds__(256)
void prep_A1(const float* __restrict__ X, const float* __restrict__ g,
             const float* __restrict__ b, short* __restrict__ Ah, short* __restrict__ Al)
{
    int w = threadIdx.x >> 6, lane = threadIdx.x & 63;
    int row = blockIdx.x * 4 + w;
    const float4* xr = (const float4*)(X + (size_t)row * KDIM);
    float4 xv[3]; float s = 0.f, ss = 0.f;
#pragma unroll
    for (int i = 0; i < 3; ++i) {
        xv[i] = xr[lane + i * 64];
        s  += xv[i].x + xv[i].y + xv[i].z + xv[i].w;
        ss += xv[i].x * xv[i].x + xv[i].y * xv[i].y + xv[i].z * xv[i].z + xv[i].w * xv[i].w;
    }
    s = wave_sum(s); ss = wave_sum(ss);
    float m = s * (1.f / 768.f), var = ss * (1.f / 768.f) - m * m;
    float sa = rsqrtf(var + 1e-5f), ta = -m * sa;
#pragma unroll
    for (int i = 0; i < 3; ++i) {
        int idx = lane + i * 64;
        float4 gv = ((const float4*)g)[idx];
        float4 bv = ((const float4*)b)[idx];
        float a0 = fmaf(fmaf(xv[i].x, sa, ta), gv.x, bv.x);
        float a1 = fmaf(fmaf(xv[i].y, sa, ta), gv.y, bv.y);
        float a2 = fmaf(fmaf(xv[i].z, sa, ta), gv.z, bv.z);
        float a3 = fmaf(fmaf(xv[i].w, sa, ta), gv.w, bv.w);
        short h0 = f2bf(a0), h1 = f2bf(a1), h2 = f2bf(a2), h3 = f2bf(a3);
        ushort4 hv, lv;
        hv.x = (uint16_t)h0; hv.y = (uint16_t)h1; hv.z = (uint16_t)h2; hv.w = (uint16_t)h3;
        lv.x = (uint16_t)f2bf(a0 - bf2f(h0)); lv.y = (uint16_t)f2bf(a1 - bf2f(h1));
        lv.z = (uint16_t)f2bf(a2 - bf2f(h2)); lv.w = (uint16_t)f2bf(a3 - bf2f(h3));
        ((ushort4*)(Ah + (size_t)row * KDIM))[idx] = hv;
        ((ushort4*)(Al + (size_t)row * KDIM))[idx] = lv;
    }
}

// ---------------------------------------------------------------------------
// prep_A2: fused gate(tanh dot) + LN2 stats + affine + split. One wave per row.
__global__ __launch_bounds__(256)
void prep_A2(const short* __restrict__ vph, const short* __restrict__ vpl,
             const float* __restrict__ qa_p, const float* __restrict__ g,
             const float* __restrict__ b, short* __restrict__ Ah, short* __restrict__ Al,
             int chunk_off)
{
    int w = threadIdx.x >> 6, lane = threadIdx.x & 63;
    int row = blockIdx.x * 4 + w;
    int bidx = (chunk_off + row) >> 5;
    const ushort4* hr = (const ushort4*)(vph + (size_t)row * KDIM);
    const ushort4* lr = (const ushort4*)(vpl + (size_t)row * KDIM);
    const float4*  qr = (const float4*)(qa_p + (size_t)bidx * KDIM);
    float vp[12]; float s = 0.f, ss = 0.f, d = 0.f;
#pragma unroll
    for (int i = 0; i < 3; ++i) {
        ushort4 hv = hr[lane + i * 64];
        ushort4 lv = lr[lane + i * 64];
        float4  qv = qr[lane + i * 64];
        float v0 = bf2f((short)hv.x) + bf2f((short)lv.x);
        float v1 = bf2f((short)hv.y) + bf2f((short)lv.y);
        float v2 = bf2f((short)hv.z) + bf2f((short)lv.z);
        float v3 = bf2f((short)hv.w) + bf2f((short)lv.w);
        vp[i * 4 + 0] = v0; vp[i * 4 + 1] = v1; vp[i * 4 + 2] = v2; vp[i * 4 + 3] = v3;
        s  += v0 + v1 + v2 + v3;
        ss += v0 * v0 + v1 * v1 + v2 * v2 + v3 * v3;
        d  += v0 * qv.x + v1 * qv.y + v2 * qv.z + v3 * qv.w;
    }
    s = wave_sum(s); ss = wave_sum(ss); d = wave_sum(d);
    float gate = tanhf(d);
    float m = s * (1.f / 768.f), var = ss * (1.f / 768.f) - m * m;
    float den = rsqrtf(gate * gate * var + 1e-5f);
    float sa = gate * den, ta = -gate * m * den;
#pragma unroll
    for (int i = 0; i < 3; ++i) {
        int idx = lane + i * 64;
        float4 gv = ((const float4*)g)[idx];
        float4 bv = ((const float4*)b)[idx];
        float a0 = fmaf(fmaf(vp[i * 4 + 0], sa, ta), gv.x, bv.x);
        float a1 = fmaf(fmaf(vp[i * 4 + 1], sa, ta), gv.y, bv.y);
        float a2 = fmaf(fmaf(vp[i * 4 + 2], sa, ta), gv.z, bv.z);
        float a3 = fmaf(fmaf(vp[i * 4 + 3], sa, ta), gv.w, bv.w);
        short h0 = f2bf(a0), h1 = f2bf(a1), h2 = f2bf(a2), h3 = f2bf(a3);
        ushort4 hv, lv;
        hv.x = (uint16_t)h0; hv.y = (uint16_t)h1; hv.z = (uint16_t)h2; hv.w = (uint16_t)h3;
        lv.x = (uint16_t)f2bf(a0 - bf2f(h0)); lv.y = (uint16_t)f2bf(a1 - bf2f(h1));
        lv.z = (uint16_t)f2bf(a2 - bf2f(h2)); lv.w = (uint16_t)f2bf(a3 - bf2f(h3));
        ((ushort4*)(Ah + (size_t)row * KDIM))[idx] = hv;
        ((ushort4*)(Al + (size_t)row * KDIM))[idx] = lv;
    }
}

// ---------------------------------------------------------------------------
// prep_W: transpose + hi/lo split.  W[k][n] f32 -> Bh/Bl[n][k] bf16.
__global__ __launch_bounds__(256)
void prep_W(const float* __restrict__ W, short* __restrict__ Bh, short* __restrict__ Bl, int N)
{
    __shared__ float t[32][33];
    int bx = blockIdx.x, by = blockIdx.y;          // bx: n-tile, by: k-tile
    int lx = threadIdx.x & 31, ly = threadIdx.x >> 5;   // ly 0..7
#pragma unroll
    for (int r = 0; r < 32; r += 8)
        t[ly + r][lx] = W[(size_t)(by * 32 + ly + r) * N + bx * 32 + lx];
    __syncthreads();
#pragma unroll
    for (int r = 0; r < 32; r += 8) {
        float v = t[lx][ly + r];                   // kk=lx, nn=ly+r
        short hi = f2bf(v);
        size_t o = (size_t)(bx * 32 + ly + r) * KDIM + by * 32 + lx;
        Bh[o] = hi;
        Bl[o] = f2bf(v - bf2f(hi));
    }
}

// ---------------------------------------------------------------------------
// Split-bf16 MFMA GEMM.  A[M][768] hi/lo, B[N][768] hi/lo (pre-transposed).
// 128x128 tile, BK=32, 4 waves, 16x16x32 MFMA, 3 mfma per fragment pair.
// LDS: 4 segs of 8KB (Ah,Al,Bh,Bl); rows 64B; slot-XOR swizzle (2-way max).
// MODE 0: out gelu -> Oh/Ol bf16 hi/lo.   MODE 1: partial row-dot with w2.
template<int N, int MODE>
__global__ __launch_bounds__(256)
void gemm_mfma(const short* __restrict__ Ah, const short* __restrict__ Al,
               const short* __restrict__ Bh, const short* __restrict__ Bl,
               const float* __restrict__ bias,
               short* __restrict__ Oh, short* __restrict__ Ol,
               const float* __restrict__ w2, float* __restrict__ partials, int chunk_off)
{
    __shared__ __align__(16) char lds[32768];
    const int tid = threadIdx.x;
    const int w = tid >> 6, lane = tid & 63;
    const int lr = lane & 15, lh = lane >> 4;
    const int wr = w >> 1, wc = w & 1;
    const int row0 = blockIdx.y * 128;
    const int col0 = blockIdx.x * 128;

    f32x4 acc[4][4] = {};

    const short* sb = (w == 0) ? Ah : (w == 1) ? Al : (w == 2) ? Bh : Bl;
    const int rb = (w < 2) ? row0 : col0;
    char* lseg = lds + w * 8192;

    for (int k0 = 0; k0 < KDIM; k0 += 32) {
        // stage: each wave DMAs its 8KB segment (16 rows x 64B per issue)
#pragma unroll
        for (int j = 0; j < 8; ++j) {
            int r = j * 16 + (lane >> 2);
            int h = (lane & 3) ^ ((r >> 1) & 3);            // inverse swizzle on source
            gl_lds16(sb + (size_t)(rb + r) * KDIM + k0 + h * 8, lseg + j * 1024);
        }
        __syncthreads();

        short8v ah[4], al[4], bh[4], bl[4];
#pragma unroll
        for (int i = 0; i < 4; ++i) {
            int ra = wr * 64 + i * 16 + lr;
            int sa = lh ^ ((ra >> 1) & 3);                  // swizzled read
            ah[i] = *(const short8v*)(lds + ra * 64 + sa * 16);
            al[i] = *(const short8v*)(lds + 8192 + ra * 64 + sa * 16);
            int rn = wc * 64 + i * 16 + lr;
            int sn = lh ^ ((rn >> 1) & 3);
            bh[i] = *(const short8v*)(lds + 16384 + rn * 64 + sn * 16);
            bl[i] = *(const short8v*)(lds + 24576 + rn * 64 + sn * 16);
        }
#pragma unroll
        for (int i = 0; i < 4; ++i)
#pragma unroll
            for (int j = 0; j < 4; ++j) {
                acc[i][j] = __builtin_amdgcn_mfma_f32_16x16x32_bf16(ah[i], bh[j], acc[i][j], 0, 0, 0);
                acc[i][j] = __builtin_amdgcn_mfma_f32_16x16x32_bf16(ah[i], bl[j], acc[i][j], 0, 0, 0);
                acc[i][j] = __builtin_amdgcn_mfma_f32_16x16x32_bf16(al[i], bh[j], acc[i][j], 0, 0, 0);
            }
        __syncthreads();
    }

    if (MODE == 0) {
#pragma unroll
        for (int i = 0; i < 4; ++i)
#pragma unroll
            for (int j = 0; j < 4; ++j) {
                int n = col0 + wc * 64 + j * 16 + lr;
                float bv = bias[n];
#pragma unroll
                for (int q = 0; q < 4; ++q) {
                    int m = row0 + wr * 64 + i * 16 + lh * 4 + q;
                    float gv = gelu_erf(acc[i][j][q] + bv);
                    short hi = f2bf(gv);
                    Oh[(size_t)m * N + n] = hi;
                    Ol[(size_t)m * N + n] = f2bf(gv - bf2f(hi));
                }
            }
    } else {
        float rs[4][4] = {};
#pragma unroll
        for (int i = 0; i < 4; ++i)
#pragma unroll
            for (int j = 0; j < 4; ++j) {
                int n = col0 + wc * 64 + j * 16 + lr;
                float bv = bias[n], wv = w2[n];
#pragma unroll
                for (int q = 0; q < 4; ++q)
                    rs[i][q] += gelu_erf(acc[i][j][q] + bv) * wv;
            }
#pragma unroll
        for (int i = 0; i < 4; ++i)
#pragma unroll
            for (int q = 0; q < 4; ++q) {
                float v = rs[i][q];
                v += __shfl_xor(v, 1); v += __shfl_xor(v, 2);
                v += __shfl_xor(v, 4); v += __shfl_xor(v, 8);
                if (lr == 0) {
                    int m = chunk_off + row0 + wr * 64 + i * 16 + lh * 4 + q;
                    partials[(size_t)(blockIdx.x * 2 + wc) * 65536 + m] = v;
                }
            }
    }
}

// ---------------------------------------------------------------------------
// f32 fallback GEMM for the small qa projection (round-0 kernel).
constexpr int BKF = 16;
__global__ __launch_bounds__(256)
void rowstats(const float* __restrict__ X, float2* __restrict__ st, int M)
{
    int wave = threadIdx.x >> 6, lane = threadIdx.x & 63;
    int row = blockIdx.x * 4 + wave;
    if (row >= M) return;
    const float4* xr = reinterpret_cast<const float4*>(X + (size_t)row * KDIM);
    float s = 0.f, ss = 0.f;
#pragma unroll
    for (int i = 0; i < 3; ++i) {
        float4 v = xr[lane + i * 64];
        s  += v.x + v.y + v.z + v.w;
        ss += v.x * v.x + v.y * v.y + v.z * v.z + v.w * v.w;
    }
    s = wave_sum(s); ss = wave_sum(ss);
    if (lane == 0) {
        float m = s * (1.0f / 768.0f);
        float var = ss * (1.0f / 768.0f) - m * m;
        float rstd = rsqrtf(var + 1e-5f);
        st[row] = make_float2(rstd, -m * rstd);
    }
}

template<int BM, int BN, int TM, int TN>
__global__ __launch_bounds__(256)
void gemm_fused(const float* __restrict__ X, const float2* __restrict__ st,
                const float* __restrict__ gw, const float* __restrict__ gb,
                const float* __restrict__ W, const float* __restrict__ bias,
                float* __restrict__ out, int M, int N)
{
    static_assert((BM / TM) * (BN / TN) == 256, "256 threads");
    __shared__ float As[BKF][BM];
    __shared__ float Bs[BKF][BN];
    const int t = threadIdx.x;
    constexpr int TXN = BN / TN;
    const int tx = t % TXN;
    const int ty = t / TXN;
    const int row0 = blockIdx.y * BM;
    const int col0 = blockIdx.x * BN;
    float acc[TM][TN] = {};
    constexpr int A_IT = BM * BKF / 4 / 256;
    constexpr int B_IT = BKF * BN / 4 / 256;
    for (int k0 = 0; k0 < KDIM; k0 += BKF) {
#pragma unroll
        for (int i = 0; i < A_IT; ++i) {
            int idx = t + i * 256;
            int r = idx >> 2;
            int c = (idx & 3) << 2;
            float4 xv = *reinterpret_cast<const float4*>(X + (size_t)(row0 + r) * KDIM + k0 + c);
            float2 s = st[row0 + r];
            float4 gv = *reinterpret_cast<const float4*>(gw + k0 + c);
            float4 bv = *reinterpret_cast<const float4*>(gb + k0 + c);
            As[c + 0][r] = fmaf(fmaf(xv.x, s.x, s.y), gv.x, bv.x);
            As[c + 1][r] = fmaf(fmaf(xv.y, s.x, s.y), gv.y, bv.y);
            As[c + 2][r] = fmaf(fmaf(xv.z, s.x, s.y), gv.z, bv.z);
            As[c + 3][r] = fmaf(fmaf(xv.w, s.x, s.y), gv.w, bv.w);
        }
#pragma unroll
        for (int i = 0; i < B_IT; ++i) {
            int idx = t + i * 256;
            int r = idx / (BN / 4);
            int c = (idx % (BN / 4)) << 2;
            *reinterpret_cast<float4*>(&Bs[r][c]) =
                *reinterpret_cast<const float4*>(W + (size_t)(k0 + r) * N + col0 + c);
        }
        __syncthreads();
#pragma unroll
        for (int kk = 0; kk < BKF; ++kk) {
            float a[TM], b[TN];
#pragma unroll
            for (int i = 0; i < TM; i += 4)
                *reinterpret_cast<float4*>(&a[i]) = *reinterpret_cast<const float4*>(&As[kk][ty * TM + i]);
#pragma unroll
            for (int j = 0; j < TN; j += 4)
                *reinterpret_cast<float4*>(&b[j]) = *reinterpret_cast<const float4*>(&Bs[kk][tx * TN + j]);
#pragma unroll
            for (int i = 0; i < TM; ++i)
#pragma unroll
                for (int j = 0; j < TN; ++j)
                    acc[i][j] = fmaf(a[i], b[j], acc[i][j]);
        }
        __syncthreads();
    }
#pragma unroll
    for (int i = 0; i < TM; ++i) {
        size_t row = row0 + ty * TM + i;
#pragma unroll
        for (int j = 0; j < TN; j += 4) {
            int col = col0 + tx * TN + j;
            float4 o;
            o.x = gelu_erf(acc[i][j + 0] + bias[col + 0]);
            o.y = gelu_erf(acc[i][j + 1] + bias[col + 1]);
            o.z = gelu_erf(acc[i][j + 2] + bias[col + 2]);
            o.w = gelu_erf(acc[i][j + 3] + bias[col + 3]);
            *reinterpret_cast<float4*>(out + row * N + col) = o;
        }
    }
}

// ---------------------------------------------------------------------------
// head: logits = sum(partials)+b2 -> softmax -> smooth -> softmax -> decode.
__global__ __launch_bounds__(64)
void head_kernel(const float* __restrict__ partials, const float* __restrict__ b2,
                 const float* __restrict__ sigma_p, float* __restrict__ out)
{
    int b = blockIdx.x, lane = threadIdx.x;
    __shared__ float ok[36];
    __shared__ float kg[32];
    __shared__ int sel[2];

    if (lane < 36) ok[lane] = 0.f;
    __syncthreads();

    float x = -3.4e38f;
    if (lane < 32) {
        int row = b * 32 + lane;
        x = b2[0];
#pragma unroll
        for (int p = 0; p < 6; ++p) x += partials[(size_t)p * 65536 + row];
    }
    float mx = wave_max(x);
    float e = (lane < 32) ? expf(x - mx) : 0.f;
    float sum = wave_sum(e);
    float ori = e / sum;
    if (lane < 32) {
        out[OFF_ORI + b * 32 + lane] = ori;
        ok[lane + 2] = ori;
    }
    __syncthreads();

    float sg = sigma_p[0];
    float kern[5]; float ks = 0.f;
#pragma unroll
    for (int k = 0; k < 5; ++k) { float xx = (float)(k - 2) / sg; kern[k] = expf(-0.5f * xx * xx); ks += kern[k]; }
    float sm = -3.4e38f;
    if (lane < 32) {
        sm = 0.f;
#pragma unroll
        for (int k = 0; k < 5; ++k) sm += (kern[k] / ks) * ok[lane + k];
    }
    float mx2 = wave_max(sm);
    float e2 = (lane < 32) ? expf(sm - mx2) : 0.f;
    float sum2 = wave_sum(e2);
    float kgv = e2 / sum2;
    if (lane < 32) {
        out[OFF_KG + b * 32 + lane] = kgv;
        kg[lane] = kgv;
    }
    __syncthreads();

    if (lane == 0) {
        int pm = 0; float bv = kg[0];
        for (int i = 1; i < 32; ++i) if (kg[i] > bv) { bv = kg[i]; pm = i; }
        float cum[33]; cum[0] = 0.f;
        for (int i = 0; i < 32; ++i) cum[i + 1] = cum[i] + kg[i];
        float bs = -3.4e38f; int bst = 0, ben = 0;
        const int wsz[3] = {1, 3, 5};
        for (int wi = 0; wi < 3; ++wi) {
            int w = wsz[wi];
            for (int s = 0; s + w <= 32; ++s) {
                if (pm >= s && pm < s + w) {
                    float sc = cum[s + w] - cum[s];
                    if (sc > bs) { bs = sc; bst = s; ben = s + w; }
                }
            }
        }
        out[OFF_MI + b * 2 + 0] = (float)bst;
        out[OFF_MI + b * 2 + 1] = (float)ben;
        out[OFF_ST + b] = (float)bst / 31.0f;
        out[OFF_ET + b] = (float)ben / 31.0f;
        sel[0] = bst; sel[1] = ben;
    }
    __syncthreads();
    if (lane < 32)
        out[OFF_MASK + b * 32 + lane] = (lane >= sel[0] && lane <= sel[1]) ? 1.0f : 0.0f;
}

// ---------------------------------------------------------------------------
extern "C" void kernel_launch(void* const* d_in, const int* in_sizes, int n_in,
                              void* d_out, int out_size, void* d_ws, size_t ws_size,
                              hipStream_t stream)
{
    const float* v      = (const float*)d_in[0];
    const float* qa     = (const float*)d_in[1];
    const float* vp_lng = (const float*)d_in[2];
    const float* vp_lnb = (const float*)d_in[3];
    const float* vp_w   = (const float*)d_in[4];
    const float* vp_b   = (const float*)d_in[5];
    const float* qp_lng = (const float*)d_in[6];
    const float* qp_lnb = (const float*)d_in[7];
    const float* qp_w   = (const float*)d_in[8];
    const float* qp_b   = (const float*)d_in[9];
    const float* g_lng  = (const float*)d_in[10];
    const float* g_lnb  = (const float*)d_in[11];
    const float* g_w1   = (const float*)d_in[12];
    const float* g_b1   = (const float*)d_in[13];
    const float* g_w2   = (const float*)d_in[14];
    const float* g_b2   = (const float*)d_in[15];
    const float* sigma  = (const float*)d_in[16];
    float* outf = (float*)d_out;

    // workspace layout (~213 MB)
    short* A1h = (short*)d_ws;                   // CHUNK*768
    short* A1l = A1h + (size_t)CHUNK * KDIM;
    short* vph = A1l + (size_t)CHUNK * KDIM;
    short* vpl = vph + (size_t)CHUNK * KDIM;
    short* B1h = vpl + (size_t)CHUNK * KDIM;     // 768*768
    short* B1l = B1h + 768 * KDIM;
    short* B2h = B1l + 768 * KDIM;               // 384*768
    short* B2l = B2h + 384 * KDIM;
    float* qa_p = (float*)(B2l + 384 * KDIM);    // 2048*768
    float* st_qa = qa_p + 2048 * KDIM;           // 2048*2
    float* partials = st_qa + 4096;              // 6*65536

    // qa path (small, f32 vector GEMM)
    rowstats<<<512, 256, 0, stream>>>(qa, (float2*)st_qa, 2048);
    gemm_fused<64, 64, 4, 4><<<dim3(12, 32), 256, 0, stream>>>(
        qa, (const float2*)st_qa, qp_lng, qp_lnb, qp_w, qp_b, qa_p, 2048, 768);

    // weight transpose + split
    prep_W<<<dim3(24, 24), 256, 0, stream>>>(vp_w, B1h, B1l, 768);
    prep_W<<<dim3(12, 24), 256, 0, stream>>>(g_w1, B2h, B2l, 384);

    for (int c = 0; c < 65536; c += CHUNK) {
        prep_A1<<<CHUNK / 4, 256, 0, stream>>>(v + (size_t)c * KDIM, vp_lng, vp_lnb, A1h, A1l);
        gemm_mfma<768, 0><<<dim3(6, CHUNK / 128), 256, 0, stream>>>(
            A1h, A1l, B1h, B1l, vp_b, vph, vpl, nullptr, nullptr, 0);
        prep_A2<<<CHUNK / 4, 256, 0, stream>>>(vph, vpl, qa_p, g_lng, g_lnb, A1h, A1l, c);
        gemm_mfma<384, 1><<<dim3(3, CHUNK / 128), 256, 0, stream>>>(
            A1h, A1l, B2h, B2l, g_b1, nullptr, nullptr, g_w2, partials, c);
    }

    head_kernel<<<2048, 64, 0, stream>>>(partials, g_b2, sigma, outf);
}

// Round 3
// 692.736 us; speedup vs baseline: 2.1835x; 1.1098x over previous
//
#include <hip/hip_runtime.h>
#include <math.h>
#include <stdint.h>

// ---------------------------------------------------------------------------
// GroundingModule — round 3: split-bf16 GEMMs, double-buffered 8-wave tiles.
//   GEMM1: 256x256 tile, GEMM2: 128x384 tile (fused logits). 2-phase schedule:
//   stage(next) -> ds_read(cur) -> MFMA -> barrier (implicit vmcnt drain).
// ---------------------------------------------------------------------------

#define DEV __device__ __forceinline__

typedef __attribute__((ext_vector_type(8))) short short8v;   // 8 bf16
typedef __attribute__((ext_vector_type(4))) float f32x4;

constexpr int KDIM  = 768;
constexpr int CHUNK = 32768;

// output offsets (floats) in return order
constexpr int OFF_KG   = 0;
constexpr int OFF_MI   = 65536;
constexpr int OFF_ST   = 69632;
constexpr int OFF_ET   = 71680;
constexpr int OFF_MASK = 73728;
constexpr int OFF_ORI  = 139264;

DEV float gelu_erf(float x) { return 0.5f * x * (1.0f + erff(x * 0.70710678118654752f)); }
DEV float wave_sum(float v) { for (int o = 32; o; o >>= 1) v += __shfl_xor(v, o); return v; }
DEV float wave_max(float v) { for (int o = 32; o; o >>= 1) v = fmaxf(v, __shfl_xor(v, o)); return v; }

DEV short f2bf(float x) {                       // f32 -> bf16 (RNE)
    uint32_t u = __builtin_bit_cast(uint32_t, x);
    u = u + 0x7fffu + ((u >> 16) & 1u);
    return (short)(u >> 16);
}
DEV float bf2f(short b) {
    uint32_t u = ((uint32_t)(uint16_t)b) << 16;
    return __builtin_bit_cast(float, u);
}

DEV void gl_lds16(const void* g, void* l) {     // async 16B/lane global->LDS
    __builtin_amdgcn_global_load_lds(
        (const __attribute__((address_space(1))) uint32_t*)g,
        (__attribute__((address_space(3))) uint32_t*)l, 16, 0, 0);
}

// ---------------------------------------------------------------------------
// prep_A1: fused rowstats + LN-affine + hi/lo split.  One wave per row.
__global__ __launch_bounds__(256)
void prep_A1(const float* __restrict__ X, const float* __restrict__ g,
             const float* __restrict__ b, short* __restrict__ Ah, short* __restrict__ Al)
{
    int w = threadIdx.x >> 6, lane = threadIdx.x & 63;
    int row = blockIdx.x * 4 + w;
    const float4* xr = (const float4*)(X + (size_t)row * KDIM);
    float4 xv[3]; float s = 0.f, ss = 0.f;
#pragma unroll
    for (int i = 0; i < 3; ++i) {
        xv[i] = xr[lane + i * 64];
        s  += xv[i].x + xv[i].y + xv[i].z + xv[i].w;
        ss += xv[i].x * xv[i].x + xv[i].y * xv[i].y + xv[i].z * xv[i].z + xv[i].w * xv[i].w;
    }
    s = wave_sum(s); ss = wave_sum(ss);
    float m = s * (1.f / 768.f), var = ss * (1.f / 768.f) - m * m;
    float sa = rsqrtf(var + 1e-5f), ta = -m * sa;
#pragma unroll
    for (int i = 0; i < 3; ++i) {
        int idx = lane + i * 64;
        float4 gv = ((const float4*)g)[idx];
        float4 bv = ((const float4*)b)[idx];
        float a0 = fmaf(fmaf(xv[i].x, sa, ta), gv.x, bv.x);
        float a1 = fmaf(fmaf(xv[i].y, sa, ta), gv.y, bv.y);
        float a2 = fmaf(fmaf(xv[i].z, sa, ta), gv.z, bv.z);
        float a3 = fmaf(fmaf(xv[i].w, sa, ta), gv.w, bv.w);
        short h0 = f2bf(a0), h1 = f2bf(a1), h2 = f2bf(a2), h3 = f2bf(a3);
        ushort4 hv, lv;
        hv.x = (uint16_t)h0; hv.y = (uint16_t)h1; hv.z = (uint16_t)h2; hv.w = (uint16_t)h3;
        lv.x = (uint16_t)f2bf(a0 - bf2f(h0)); lv.y = (uint16_t)f2bf(a1 - bf2f(h1));
        lv.z = (uint16_t)f2bf(a2 - bf2f(h2)); lv.w = (uint16_t)f2bf(a3 - bf2f(h3));
        ((ushort4*)(Ah + (size_t)row * KDIM))[idx] = hv;
        ((ushort4*)(Al + (size_t)row * KDIM))[idx] = lv;
    }
}

// ---------------------------------------------------------------------------
// prep_A2: fused gate(tanh dot) + LN2 stats + affine + split. One wave per row.
__global__ __launch_bounds__(256)
void prep_A2(const short* __restrict__ vph, const short* __restrict__ vpl,
             const float* __restrict__ qa_p, const float* __restrict__ g,
             const float* __restrict__ b, short* __restrict__ Ah, short* __restrict__ Al,
             int chunk_off)
{
    int w = threadIdx.x >> 6, lane = threadIdx.x & 63;
    int row = blockIdx.x * 4 + w;
    int bidx = (chunk_off + row) >> 5;
    const ushort4* hr = (const ushort4*)(vph + (size_t)row * KDIM);
    const ushort4* lr = (const ushort4*)(vpl + (size_t)row * KDIM);
    const float4*  qr = (const float4*)(qa_p + (size_t)bidx * KDIM);
    float vp[12]; float s = 0.f, ss = 0.f, d = 0.f;
#pragma unroll
    for (int i = 0; i < 3; ++i) {
        ushort4 hv = hr[lane + i * 64];
        ushort4 lv = lr[lane + i * 64];
        float4  qv = qr[lane + i * 64];
        float v0 = bf2f((short)hv.x) + bf2f((short)lv.x);
        float v1 = bf2f((short)hv.y) + bf2f((short)lv.y);
        float v2 = bf2f((short)hv.z) + bf2f((short)lv.z);
        float v3 = bf2f((short)hv.w) + bf2f((short)lv.w);
        vp[i * 4 + 0] = v0; vp[i * 4 + 1] = v1; vp[i * 4 + 2] = v2; vp[i * 4 + 3] = v3;
        s  += v0 + v1 + v2 + v3;
        ss += v0 * v0 + v1 * v1 + v2 * v2 + v3 * v3;
        d  += v0 * qv.x + v1 * qv.y + v2 * qv.z + v3 * qv.w;
    }
    s = wave_sum(s); ss = wave_sum(ss); d = wave_sum(d);
    float gate = tanhf(d);
    float m = s * (1.f / 768.f), var = ss * (1.f / 768.f) - m * m;
    float den = rsqrtf(gate * gate * var + 1e-5f);
    float sa = gate * den, ta = -gate * m * den;
#pragma unroll
    for (int i = 0; i < 3; ++i) {
        int idx = lane + i * 64;
        float4 gv = ((const float4*)g)[idx];
        float4 bv = ((const float4*)b)[idx];
        float a0 = fmaf(fmaf(vp[i * 4 + 0], sa, ta), gv.x, bv.x);
        float a1 = fmaf(fmaf(vp[i * 4 + 1], sa, ta), gv.y, bv.y);
        float a2 = fmaf(fmaf(vp[i * 4 + 2], sa, ta), gv.z, bv.z);
        float a3 = fmaf(fmaf(vp[i * 4 + 3], sa, ta), gv.w, bv.w);
        short h0 = f2bf(a0), h1 = f2bf(a1), h2 = f2bf(a2), h3 = f2bf(a3);
        ushort4 hv, lv;
        hv.x = (uint16_t)h0; hv.y = (uint16_t)h1; hv.z = (uint16_t)h2; hv.w = (uint16_t)h3;
        lv.x = (uint16_t)f2bf(a0 - bf2f(h0)); lv.y = (uint16_t)f2bf(a1 - bf2f(h1));
        lv.z = (uint16_t)f2bf(a2 - bf2f(h2)); lv.w = (uint16_t)f2bf(a3 - bf2f(h3));
        ((ushort4*)(Ah + (size_t)row * KDIM))[idx] = hv;
        ((ushort4*)(Al + (size_t)row * KDIM))[idx] = lv;
    }
}

// ---------------------------------------------------------------------------
// prep_W: transpose + hi/lo split.  W[k][n] f32 -> Bh/Bl[n][k] bf16.
__global__ __launch_bounds__(256)
void prep_W(const float* __restrict__ W, short* __restrict__ Bh, short* __restrict__ Bl, int N)
{
    __shared__ float t[32][33];
    int bx = blockIdx.x, by = blockIdx.y;
    int lx = threadIdx.x & 31, ly = threadIdx.x >> 5;
#pragma unroll
    for (int r = 0; r < 32; r += 8)
        t[ly + r][lx] = W[(size_t)(by * 32 + ly + r) * N + bx * 32 + lx];
    __syncthreads();
#pragma unroll
    for (int r = 0; r < 32; r += 8) {
        float v = t[lx][ly + r];
        short hi = f2bf(v);
        size_t o = (size_t)(bx * 32 + ly + r) * KDIM + by * 32 + lx;
        Bh[o] = hi;
        Bl[o] = f2bf(v - bf2f(hi));
    }
}

// ---------------------------------------------------------------------------
// Split-bf16 MFMA GEMM, 512 threads = 8 waves, double-buffered LDS, BK=32.
//   A[M][768] hi/lo, B[N][768] hi/lo (pre-transposed).  3 MFMA per frag pair.
//   MODE 0: out = gelu(.) -> Oh/Ol bf16 hi/lo.
//   MODE 1: partial row-dot with w2 -> partials[wn][row] (WN partials/row).
template<int BM, int BN, int WM, int WN, int MODE>
__global__ __launch_bounds__(512, 2)
void gemm_mfma(const short* __restrict__ Ah_g, const short* __restrict__ Al_g,
               const short* __restrict__ Bh_g, const short* __restrict__ Bl_g,
               const float* __restrict__ bias,
               short* __restrict__ Oh, short* __restrict__ Ol, int N,
               const float* __restrict__ w2, float* __restrict__ partials, int chunk_off)
{
    constexpr int MF = BM / (16 * WM);           // M fragments per wave
    constexpr int NF = BN / (16 * WN);           // N fragments per wave
    constexpr int ABYTES = BM * 64;              // one part, one K-step slice
    constexpr int BBYTES = BN * 64;
    constexpr int BUFSZ  = 2 * ABYTES + 2 * BBYTES;
    extern __shared__ __align__(16) char lds[];  // 2 * BUFSZ (128 KB)

    const int tid = threadIdx.x;
    const int w = tid >> 6, lane = tid & 63;
    const int lr = lane & 15, lh = lane >> 4;
    const int wm = w / WN, wn = w % WN;

    // XCD-aware bijective swizzle (nwg % 8 == 0 by launch config)
    const int gx = gridDim.x, nwg = gx * gridDim.y;
    int idx = blockIdx.y * gx + blockIdx.x;
    int wid = (idx & 7) * (nwg >> 3) + (idx >> 3);
    const int bx = wid % gx, by = wid / gx;
    const int row0 = by * BM, col0 = bx * BN;

    f32x4 acc[MF][NF] = {};

    // staging addresses: thread t covers 16B at (row r_= t>>2, slot t&3),
    // source column pre-swizzled so LDS stays linear (both-sides swizzle).
    const int r_ = tid >> 2;
    const int slot_ = ((tid & 3) ^ ((r_ >> 1) & 3)) * 8;   // in shorts
    const int wsub = (tid >> 6) * 1024;

    auto stage = [&](int buf, int k0) {
        char* base = lds + buf * BUFSZ;
        const int kk = k0 + slot_;
#pragma unroll
        for (int j = 0; j < BM / 128; ++j) {
            gl_lds16(Ah_g + (size_t)(row0 + j * 128 + r_) * KDIM + kk,
                     base + j * 8192 + wsub);
            gl_lds16(Al_g + (size_t)(row0 + j * 128 + r_) * KDIM + kk,
                     base + ABYTES + j * 8192 + wsub);
        }
#pragma unroll
        for (int j = 0; j < BN / 128; ++j) {
            gl_lds16(Bh_g + (size_t)(col0 + j * 128 + r_) * KDIM + kk,
                     base + 2 * ABYTES + j * 8192 + wsub);
            gl_lds16(Bl_g + (size_t)(col0 + j * 128 + r_) * KDIM + kk,
                     base + 2 * ABYTES + BBYTES + j * 8192 + wsub);
        }
    };

    stage(0, 0);
    __syncthreads();

    for (int ks = 0; ks < KDIM / 32; ++ks) {
        const int cur = ks & 1;
        if (ks < KDIM / 32 - 1) stage(cur ^ 1, (ks + 1) * 32);
        __builtin_amdgcn_sched_barrier(0);        // keep stage-issue early
        const char* bb = lds + cur * BUFSZ;

        short8v bh[NF], bl[NF];
#pragma unroll
        for (int j = 0; j < NF; ++j) {
            int rn = wn * (NF * 16) + j * 16 + lr;
            int sn = (lh ^ ((rn >> 1) & 3)) * 16;
            bh[j] = *(const short8v*)(bb + 2 * ABYTES + rn * 64 + sn);
            bl[j] = *(const short8v*)(bb + 2 * ABYTES + BBYTES + rn * 64 + sn);
        }
        __builtin_amdgcn_s_setprio(1);
#pragma unroll
        for (int i = 0; i < MF; ++i) {
            int ra = wm * (MF * 16) + i * 16 + lr;
            int sa = (lh ^ ((ra >> 1) & 3)) * 16;
            short8v ah = *(const short8v*)(bb + ra * 64 + sa);
            short8v al = *(const short8v*)(bb + ABYTES + ra * 64 + sa);
#pragma unroll
            for (int j = 0; j < NF; ++j) {
                acc[i][j] = __builtin_amdgcn_mfma_f32_16x16x32_bf16(ah, bh[j], acc[i][j], 0, 0, 0);
                acc[i][j] = __builtin_amdgcn_mfma_f32_16x16x32_bf16(ah, bl[j], acc[i][j], 0, 0, 0);
                acc[i][j] = __builtin_amdgcn_mfma_f32_16x16x32_bf16(al, bh[j], acc[i][j], 0, 0, 0);
            }
        }
        __builtin_amdgcn_s_setprio(0);
        __syncthreads();
    }

    if (MODE == 0) {
#pragma unroll
        for (int i = 0; i < MF; ++i)
#pragma unroll
            for (int j = 0; j < NF; ++j) {
                int n = col0 + wn * (NF * 16) + j * 16 + lr;
                float bv = bias[n];
#pragma unroll
                for (int q = 0; q < 4; ++q) {
                    int m = row0 + wm * (MF * 16) + i * 16 + lh * 4 + q;
                    float gv = gelu_erf(acc[i][j][q] + bv);
                    short hi = f2bf(gv);
                    Oh[(size_t)m * N + n] = hi;
                    Ol[(size_t)m * N + n] = f2bf(gv - bf2f(hi));
                }
            }
    } else {
        float rs[MF][4] = {};
#pragma unroll
        for (int i = 0; i < MF; ++i)
#pragma unroll
            for (int j = 0; j < NF; ++j) {
                int n = col0 + wn * (NF * 16) + j * 16 + lr;
                float bv = bias[n], wv = w2[n];
#pragma unroll
                for (int q = 0; q < 4; ++q)
                    rs[i][q] += gelu_erf(acc[i][j][q] + bv) * wv;
            }
#pragma unroll
        for (int i = 0; i < MF; ++i)
#pragma unroll
            for (int q = 0; q < 4; ++q) {
                float vv = rs[i][q];
                vv += __shfl_xor(vv, 1); vv += __shfl_xor(vv, 2);
                vv += __shfl_xor(vv, 4); vv += __shfl_xor(vv, 8);
                if (lr == 0) {
                    int m = chunk_off + row0 + wm * (MF * 16) + i * 16 + lh * 4 + q;
                    partials[(size_t)(bx * WN + wn) * 65536 + m] = vv;
                }
            }
    }
}

// ---------------------------------------------------------------------------
// f32 fallback GEMM for the small qa projection.
constexpr int BKF = 16;
__global__ __launch_bounds__(256)
void rowstats(const float* __restrict__ X, float2* __restrict__ st, int M)
{
    int wave = threadIdx.x >> 6, lane = threadIdx.x & 63;
    int row = blockIdx.x * 4 + wave;
    if (row >= M) return;
    const float4* xr = reinterpret_cast<const float4*>(X + (size_t)row * KDIM);
    float s = 0.f, ss = 0.f;
#pragma unroll
    for (int i = 0; i < 3; ++i) {
        float4 v = xr[lane + i * 64];
        s  += v.x + v.y + v.z + v.w;
        ss += v.x * v.x + v.y * v.y + v.z * v.z + v.w * v.w;
    }
    s = wave_sum(s); ss = wave_sum(ss);
    if (lane == 0) {
        float m = s * (1.0f / 768.0f);
        float var = ss * (1.0f / 768.0f) - m * m;
        float rstd = rsqrtf(var + 1e-5f);
        st[row] = make_float2(rstd, -m * rstd);
    }
}

template<int BM, int BN, int TM, int TN>
__global__ __launch_bounds__(256)
void gemm_fused(const float* __restrict__ X, const float2* __restrict__ st,
                const float* __restrict__ gw, const float* __restrict__ gb,
                const float* __restrict__ W, const float* __restrict__ bias,
                float* __restrict__ out, int M, int N)
{
    static_assert((BM / TM) * (BN / TN) == 256, "256 threads");
    __shared__ float As[BKF][BM];
    __shared__ float Bs[BKF][BN];
    const int t = threadIdx.x;
    constexpr int TXN = BN / TN;
    const int tx = t % TXN;
    const int ty = t / TXN;
    const int row0 = blockIdx.y * BM;
    const int col0 = blockIdx.x * BN;
    float acc[TM][TN] = {};
    constexpr int A_IT = BM * BKF / 4 / 256;
    constexpr int B_IT = BKF * BN / 4 / 256;
    for (int k0 = 0; k0 < KDIM; k0 += BKF) {
#pragma unroll
        for (int i = 0; i < A_IT; ++i) {
            int idx = t + i * 256;
            int r = idx >> 2;
            int c = (idx & 3) << 2;
            float4 xv = *reinterpret_cast<const float4*>(X + (size_t)(row0 + r) * KDIM + k0 + c);
            float2 s = st[row0 + r];
            float4 gv = *reinterpret_cast<const float4*>(gw + k0 + c);
            float4 bv = *reinterpret_cast<const float4*>(gb + k0 + c);
            As[c + 0][r] = fmaf(fmaf(xv.x, s.x, s.y), gv.x, bv.x);
            As[c + 1][r] = fmaf(fmaf(xv.y, s.x, s.y), gv.y, bv.y);
            As[c + 2][r] = fmaf(fmaf(xv.z, s.x, s.y), gv.z, bv.z);
            As[c + 3][r] = fmaf(fmaf(xv.w, s.x, s.y), gv.w, bv.w);
        }
#pragma unroll
        for (int i = 0; i < B_IT; ++i) {
            int idx = t + i * 256;
            int r = idx / (BN / 4);
            int c = (idx % (BN / 4)) << 2;
            *reinterpret_cast<float4*>(&Bs[r][c]) =
                *reinterpret_cast<const float4*>(W + (size_t)(k0 + r) * N + col0 + c);
        }
        __syncthreads();
#pragma unroll
        for (int kk = 0; kk < BKF; ++kk) {
            float a[TM], b[TN];
#pragma unroll
            for (int i = 0; i < TM; i += 4)
                *reinterpret_cast<float4*>(&a[i]) = *reinterpret_cast<const float4*>(&As[kk][ty * TM + i]);
#pragma unroll
            for (int j = 0; j < TN; j += 4)
                *reinterpret_cast<float4*>(&b[j]) = *reinterpret_cast<const float4*>(&Bs[kk][tx * TN + j]);
#pragma unroll
            for (int i = 0; i < TM; ++i)
#pragma unroll
                for (int j = 0; j < TN; ++j)
                    acc[i][j] = fmaf(a[i], b[j], acc[i][j]);
        }
        __syncthreads();
    }
#pragma unroll
    for (int i = 0; i < TM; ++i) {
        size_t row = row0 + ty * TM + i;
#pragma unroll
        for (int j = 0; j < TN; j += 4) {
            int col = col0 + tx * TN + j;
            float4 o;
            o.x = gelu_erf(acc[i][j + 0] + bias[col + 0]);
            o.y = gelu_erf(acc[i][j + 1] + bias[col + 1]);
            o.z = gelu_erf(acc[i][j + 2] + bias[col + 2]);
            o.w = gelu_erf(acc[i][j + 3] + bias[col + 3]);
            *reinterpret_cast<float4*>(out + row * N + col) = o;
        }
    }
}

// ---------------------------------------------------------------------------
// head: logits = sum(4 partials)+b2 -> softmax -> smooth -> softmax -> decode.
__global__ __launch_bounds__(64)
void head_kernel(const float* __restrict__ partials, const float* __restrict__ b2,
                 const float* __restrict__ sigma_p, float* __restrict__ out)
{
    int b = blockIdx.x, lane = threadIdx.x;
    __shared__ float ok[36];
    __shared__ float kg[32];
    __shared__ int sel[2];

    if (lane < 36) ok[lane] = 0.f;
    __syncthreads();

    float x = -3.4e38f;
    if (lane < 32) {
        int row = b * 32 + lane;
        x = b2[0];
#pragma unroll
        for (int p = 0; p < 4; ++p) x += partials[(size_t)p * 65536 + row];
    }
    float mx = wave_max(x);
    float e = (lane < 32) ? expf(x - mx) : 0.f;
    float sum = wave_sum(e);
    float ori = e / sum;
    if (lane < 32) {
        out[OFF_ORI + b * 32 + lane] = ori;
        ok[lane + 2] = ori;
    }
    __syncthreads();

    float sg = sigma_p[0];
    float kern[5]; float ks = 0.f;
#pragma unroll
    for (int k = 0; k < 5; ++k) { float xx = (float)(k - 2) / sg; kern[k] = expf(-0.5f * xx * xx); ks += kern[k]; }
    float sm = -3.4e38f;
    if (lane < 32) {
        sm = 0.f;
#pragma unroll
        for (int k = 0; k < 5; ++k) sm += (kern[k] / ks) * ok[lane + k];
    }
    float mx2 = wave_max(sm);
    float e2 = (lane < 32) ? expf(sm - mx2) : 0.f;
    float sum2 = wave_sum(e2);
    float kgv = e2 / sum2;
    if (lane < 32) {
        out[OFF_KG + b * 32 + lane] = kgv;
        kg[lane] = kgv;
    }
    __syncthreads();

    if (lane == 0) {
        int pm = 0; float bv = kg[0];
        for (int i = 1; i < 32; ++i) if (kg[i] > bv) { bv = kg[i]; pm = i; }
        float cum[33]; cum[0] = 0.f;
        for (int i = 0; i < 32; ++i) cum[i + 1] = cum[i] + kg[i];
        float bs = -3.4e38f; int bst = 0, ben = 0;
        const int wsz[3] = {1, 3, 5};
        for (int wi = 0; wi < 3; ++wi) {
            int w = wsz[wi];
            for (int s = 0; s + w <= 32; ++s) {
                if (pm >= s && pm < s + w) {
                    float sc = cum[s + w] - cum[s];
                    if (sc > bs) { bs = sc; bst = s; ben = s + w; }
                }
            }
        }
        out[OFF_MI + b * 2 + 0] = (float)bst;
        out[OFF_MI + b * 2 + 1] = (float)ben;
        out[OFF_ST + b] = (float)bst / 31.0f;
        out[OFF_ET + b] = (float)ben / 31.0f;
        sel[0] = bst; sel[1] = ben;
    }
    __syncthreads();
    if (lane < 32)
        out[OFF_MASK + b * 32 + lane] = (lane >= sel[0] && lane <= sel[1]) ? 1.0f : 0.0f;
}

// ---------------------------------------------------------------------------
extern "C" void kernel_launch(void* const* d_in, const int* in_sizes, int n_in,
                              void* d_out, int out_size, void* d_ws, size_t ws_size,
                              hipStream_t stream)
{
    const float* v      = (const float*)d_in[0];
    const float* qa     = (const float*)d_in[1];
    const float* vp_lng = (const float*)d_in[2];
    const float* vp_lnb = (const float*)d_in[3];
    const float* vp_w   = (const float*)d_in[4];
    const float* vp_b   = (const float*)d_in[5];
    const float* qp_lng = (const float*)d_in[6];
    const float* qp_lnb = (const float*)d_in[7];
    const float* qp_w   = (const float*)d_in[8];
    const float* qp_b   = (const float*)d_in[9];
    const float* g_lng  = (const float*)d_in[10];
    const float* g_lnb  = (const float*)d_in[11];
    const float* g_w1   = (const float*)d_in[12];
    const float* g_b1   = (const float*)d_in[13];
    const float* g_w2   = (const float*)d_in[14];
    const float* g_b2   = (const float*)d_in[15];
    const float* sigma  = (const float*)d_in[16];
    float* outf = (float*)d_out;

    // workspace layout (~215 MB)
    short* A1h = (short*)d_ws;                   // CHUNK*768
    short* A1l = A1h + (size_t)CHUNK * KDIM;
    short* vph = A1l + (size_t)CHUNK * KDIM;
    short* vpl = vph + (size_t)CHUNK * KDIM;
    short* B1h = vpl + (size_t)CHUNK * KDIM;     // 768*768
    short* B1l = B1h + 768 * KDIM;
    short* B2h = B1l + 768 * KDIM;               // 384*768
    short* B2l = B2h + 384 * KDIM;
    float* qa_p = (float*)(B2l + 384 * KDIM);    // 2048*768
    float* st_qa = qa_p + 2048 * KDIM;           // 2048*2
    float* partials = st_qa + 4096;              // 4*65536

    // qa path (small, f32 vector GEMM)
    rowstats<<<512, 256, 0, stream>>>(qa, (float2*)st_qa, 2048);
    gemm_fused<64, 64, 4, 4><<<dim3(12, 32), 256, 0, stream>>>(
        qa, (const float2*)st_qa, qp_lng, qp_lnb, qp_w, qp_b, qa_p, 2048, 768);

    // weight transpose + split
    prep_W<<<dim3(24, 24), 256, 0, stream>>>(vp_w, B1h, B1l, 768);
    prep_W<<<dim3(12, 24), 256, 0, stream>>>(g_w1, B2h, B2l, 384);

    constexpr int LDS1 = 2 * (2 * 256 * 64 + 2 * 256 * 64);   // 131072
    constexpr int LDS2 = 2 * (2 * 128 * 64 + 2 * 384 * 64);   // 131072

    for (int c = 0; c < 65536; c += CHUNK) {
        prep_A1<<<CHUNK / 4, 256, 0, stream>>>(v + (size_t)c * KDIM, vp_lng, vp_lnb, A1h, A1l);
        // v_p = gelu(A1 @ vp_w^T + vp_b): 256x256 tile, grid (3,128)=384 blocks
        gemm_mfma<256, 256, 2, 4, 0><<<dim3(3, CHUNK / 256), 512, LDS1, stream>>>(
            A1h, A1l, B1h, B1l, vp_b, vph, vpl, 768, nullptr, nullptr, 0);
        prep_A2<<<CHUNK / 4, 256, 0, stream>>>(vph, vpl, qa_p, g_lng, g_lnb, A1h, A1l, c);
        // fused h@g_w1+gelu+dot(g_w2): 128x384 tile, grid (1,256)=256 blocks
        gemm_mfma<128, 384, 2, 4, 1><<<dim3(1, CHUNK / 128), 512, LDS2, stream>>>(
            A1h, A1l, B2h, B2l, g_b1, nullptr, nullptr, 384, g_w2, partials, c);
    }

    head_kernel<<<2048, 64, 0, stream>>>(partials, g_b2, sigma, outf);
}

// Round 4
// 647.215 us; speedup vs baseline: 2.3370x; 1.0703x over previous
//
#include <hip/hip_runtime.h>
#include <math.h>
#include <stdint.h>

// ---------------------------------------------------------------------------
// GroundingModule — round 4: split-bf16 MFMA GEMMs with counted-vmcnt
// double-buffered pipeline (stage-first, vmcnt(7), raw barriers).
//   Both GEMMs: BM=256, BN=192, 512 thr / 8 waves, BK=32, LDS 2x56KB.
// ---------------------------------------------------------------------------

#define DEV __device__ __forceinline__

typedef __attribute__((ext_vector_type(8))) short short8v;   // 8 bf16
typedef __attribute__((ext_vector_type(4))) float f32x4;

constexpr int KDIM  = 768;
constexpr int CHUNK = 32768;

// output offsets (floats) in return order
constexpr int OFF_KG   = 0;
constexpr int OFF_MI   = 65536;
constexpr int OFF_ST   = 69632;
constexpr int OFF_ET   = 71680;
constexpr int OFF_MASK = 73728;
constexpr int OFF_ORI  = 139264;

DEV float gelu_erf(float x) { return 0.5f * x * (1.0f + erff(x * 0.70710678118654752f)); }
DEV float wave_sum(float v) { for (int o = 32; o; o >>= 1) v += __shfl_xor(v, o); return v; }
DEV float wave_max(float v) { for (int o = 32; o; o >>= 1) v = fmaxf(v, __shfl_xor(v, o)); return v; }

DEV short f2bf(float x) {                       // f32 -> bf16 (RNE)
    uint32_t u = __builtin_bit_cast(uint32_t, x);
    u = u + 0x7fffu + ((u >> 16) & 1u);
    return (short)(u >> 16);
}
DEV float bf2f(short b) {
    uint32_t u = ((uint32_t)(uint16_t)b) << 16;
    return __builtin_bit_cast(float, u);
}

DEV void gl_lds16(const void* g, void* l) {     // async 16B/lane global->LDS
    __builtin_amdgcn_global_load_lds(
        (const __attribute__((address_space(1))) uint32_t*)g,
        (__attribute__((address_space(3))) uint32_t*)l, 16, 0, 0);
}

// ---------------------------------------------------------------------------
// prep_A1: fused rowstats + LN-affine + hi/lo split.  One wave per row.
__global__ __launch_bounds__(256)
void prep_A1(const float* __restrict__ X, const float* __restrict__ g,
             const float* __restrict__ b, short* __restrict__ Ah, short* __restrict__ Al)
{
    int w = threadIdx.x >> 6, lane = threadIdx.x & 63;
    int row = blockIdx.x * 4 + w;
    const float4* xr = (const float4*)(X + (size_t)row * KDIM);
    float4 xv[3]; float s = 0.f, ss = 0.f;
#pragma unroll
    for (int i = 0; i < 3; ++i) {
        xv[i] = xr[lane + i * 64];
        s  += xv[i].x + xv[i].y + xv[i].z + xv[i].w;
        ss += xv[i].x * xv[i].x + xv[i].y * xv[i].y + xv[i].z * xv[i].z + xv[i].w * xv[i].w;
    }
    s = wave_sum(s); ss = wave_sum(ss);
    float m = s * (1.f / 768.f), var = ss * (1.f / 768.f) - m * m;
    float sa = rsqrtf(var + 1e-5f), ta = -m * sa;
#pragma unroll
    for (int i = 0; i < 3; ++i) {
        int idx = lane + i * 64;
        float4 gv = ((const float4*)g)[idx];
        float4 bv = ((const float4*)b)[idx];
        float a0 = fmaf(fmaf(xv[i].x, sa, ta), gv.x, bv.x);
        float a1 = fmaf(fmaf(xv[i].y, sa, ta), gv.y, bv.y);
        float a2 = fmaf(fmaf(xv[i].z, sa, ta), gv.z, bv.z);
        float a3 = fmaf(fmaf(xv[i].w, sa, ta), gv.w, bv.w);
        short h0 = f2bf(a0), h1 = f2bf(a1), h2 = f2bf(a2), h3 = f2bf(a3);
        ushort4 hv, lv;
        hv.x = (uint16_t)h0; hv.y = (uint16_t)h1; hv.z = (uint16_t)h2; hv.w = (uint16_t)h3;
        lv.x = (uint16_t)f2bf(a0 - bf2f(h0)); lv.y = (uint16_t)f2bf(a1 - bf2f(h1));
        lv.z = (uint16_t)f2bf(a2 - bf2f(h2)); lv.w = (uint16_t)f2bf(a3 - bf2f(h3));
        ((ushort4*)(Ah + (size_t)row * KDIM))[idx] = hv;
        ((ushort4*)(Al + (size_t)row * KDIM))[idx] = lv;
    }
}

// ---------------------------------------------------------------------------
// prep_A2: gate(tanh dot) + LN2 stats + affine + split. vp packed (hi|lo<<16).
__global__ __launch_bounds__(256)
void prep_A2(const uint32_t* __restrict__ vp_hl, const float* __restrict__ qa_p,
             const float* __restrict__ g, const float* __restrict__ b,
             short* __restrict__ Ah, short* __restrict__ Al, int chunk_off)
{
    int w = threadIdx.x >> 6, lane = threadIdx.x & 63;
    int row = blockIdx.x * 4 + w;
    int bidx = (chunk_off + row) >> 5;
    const uint4*  hr = (const uint4*)(vp_hl + (size_t)row * KDIM);
    const float4* qr = (const float4*)(qa_p + (size_t)bidx * KDIM);
    float vp[12]; float s = 0.f, ss = 0.f, d = 0.f;
#pragma unroll
    for (int i = 0; i < 3; ++i) {
        uint4  uv = hr[lane + i * 64];
        float4 qv = qr[lane + i * 64];
        float v0 = bf2f((short)(uv.x & 0xffff)) + bf2f((short)(uv.x >> 16));
        float v1 = bf2f((short)(uv.y & 0xffff)) + bf2f((short)(uv.y >> 16));
        float v2 = bf2f((short)(uv.z & 0xffff)) + bf2f((short)(uv.z >> 16));
        float v3 = bf2f((short)(uv.w & 0xffff)) + bf2f((short)(uv.w >> 16));
        vp[i * 4 + 0] = v0; vp[i * 4 + 1] = v1; vp[i * 4 + 2] = v2; vp[i * 4 + 3] = v3;
        s  += v0 + v1 + v2 + v3;
        ss += v0 * v0 + v1 * v1 + v2 * v2 + v3 * v3;
        d  += v0 * qv.x + v1 * qv.y + v2 * qv.z + v3 * qv.w;
    }
    s = wave_sum(s); ss = wave_sum(ss); d = wave_sum(d);
    float gate = tanhf(d);
    float m = s * (1.f / 768.f), var = ss * (1.f / 768.f) - m * m;
    float den = rsqrtf(gate * gate * var + 1e-5f);
    float sa = gate * den, ta = -gate * m * den;
#pragma unroll
    for (int i = 0; i < 3; ++i) {
        int idx = lane + i * 64;
        float4 gv = ((const float4*)g)[idx];
        float4 bv = ((const float4*)b)[idx];
        float a0 = fmaf(fmaf(vp[i * 4 + 0], sa, ta), gv.x, bv.x);
        float a1 = fmaf(fmaf(vp[i * 4 + 1], sa, ta), gv.y, bv.y);
        float a2 = fmaf(fmaf(vp[i * 4 + 2], sa, ta), gv.z, bv.z);
        float a3 = fmaf(fmaf(vp[i * 4 + 3], sa, ta), gv.w, bv.w);
        short h0 = f2bf(a0), h1 = f2bf(a1), h2 = f2bf(a2), h3 = f2bf(a3);
        ushort4 hv, lv;
        hv.x = (uint16_t)h0; hv.y = (uint16_t)h1; hv.z = (uint16_t)h2; hv.w = (uint16_t)h3;
        lv.x = (uint16_t)f2bf(a0 - bf2f(h0)); lv.y = (uint16_t)f2bf(a1 - bf2f(h1));
        lv.z = (uint16_t)f2bf(a2 - bf2f(h2)); lv.w = (uint16_t)f2bf(a3 - bf2f(h3));
        ((ushort4*)(Ah + (size_t)row * KDIM))[idx] = hv;
        ((ushort4*)(Al + (size_t)row * KDIM))[idx] = lv;
    }
}

// ---------------------------------------------------------------------------
// prep_W: transpose + hi/lo split.  W[k][n] f32 -> Bh/Bl[n][k] bf16.
__global__ __launch_bounds__(256)
void prep_W(const float* __restrict__ W, short* __restrict__ Bh, short* __restrict__ Bl, int N)
{
    __shared__ float t[32][33];
    int bx = blockIdx.x, by = blockIdx.y;
    int lx = threadIdx.x & 31, ly = threadIdx.x >> 5;
#pragma unroll
    for (int r = 0; r < 32; r += 8)
        t[ly + r][lx] = W[(size_t)(by * 32 + ly + r) * N + bx * 32 + lx];
    __syncthreads();
#pragma unroll
    for (int r = 0; r < 32; r += 8) {
        float v = t[lx][ly + r];
        short hi = f2bf(v);
        size_t o = (size_t)(bx * 32 + ly + r) * KDIM + by * 32 + lx;
        Bh[o] = hi;
        Bl[o] = f2bf(v - bf2f(hi));
    }
}

// ---------------------------------------------------------------------------
// Split-bf16 MFMA GEMM, BM=256 BN=192, 512 threads (8 waves, 2x4), BK=32.
// Counted-vmcnt double-buffer: stage(next) -> vmcnt(7) -> barrier -> compute
// -> barrier.  VMEM pipe never drains in steady state.
//   MODE 0: out = gelu(.) packed (hi | lo<<16) u32.
//   MODE 1: partial row-dot with w2 -> partials[bx*4+wn][row].
template<int MODE>
__global__ __launch_bounds__(512, 2)
void gemm_mfma(const short* __restrict__ Ah_g, const short* __restrict__ Al_g,
               const short* __restrict__ Bh_g, const short* __restrict__ Bl_g,
               const float* __restrict__ bias, uint32_t* __restrict__ O_hl, int N,
               const float* __restrict__ w2, float* __restrict__ partials, int chunk_off)
{
    constexpr int BM = 256, BN = 192;
    constexpr int SEG_A = BM * 64;               // 16384 B per stream slice
    constexpr int SEG_B = BN * 64;               // 12288 B
    constexpr int BUFSZ = 2 * SEG_A + 2 * SEG_B; // 57344 B
    extern __shared__ __align__(16) char lds[];  // 2 * BUFSZ

    const int tid = threadIdx.x;
    const int w = tid >> 6, lane = tid & 63;
    const int lr = lane & 15, lh = lane >> 4;
    const int wm = w >> 2, wn = w & 3;           // 2 x 4 wave grid

    // XCD-aware bijective swizzle (nwg % 8 == 0 by launch config)
    const int gx = gridDim.x, nwg = gx * gridDim.y;
    int idx = blockIdx.y * gx + blockIdx.x;
    int wid = (idx & 7) * (nwg >> 3) + (idx >> 3);
    const int bx = wid % gx, by = wid / gx;
    const int row0 = by * BM, col0 = bx * BN;

    f32x4 acc[8][3] = {};

    // precompute 7 per-thread stage source pointers + LDS chunk offsets
    const int r16 = lane >> 2, sl = lane & 3;
    const short* sp[7];
    int ldsoff[7];
#pragma unroll
    for (int j = 0; j < 7; ++j) {
        int c = w * 7 + j;
        const short* src; int rowb, tb;
        if (c < 16)      { src = Ah_g; rowb = c * 16;        tb = row0; }
        else if (c < 32) { src = Al_g; rowb = (c - 16) * 16; tb = row0; }
        else if (c < 44) { src = Bh_g; rowb = (c - 32) * 16; tb = col0; }
        else             { src = Bl_g; rowb = (c - 44) * 16; tb = col0; }
        int row = rowb + r16;
        int s = sl ^ ((row >> 1) & 3);
        sp[j] = src + (size_t)(tb + row) * KDIM + s * 8;
        ldsoff[j] = c * 1024;
    }

    auto stage = [&](int buf, int k0) {
        char* base = lds + buf * BUFSZ;
#pragma unroll
        for (int j = 0; j < 7; ++j)
            gl_lds16(sp[j] + k0, base + ldsoff[j]);
    };

    int cur = 0;
    stage(0, 0);

    for (int ks = 0; ks < 24; ++ks) {
        if (ks < 23) {
            stage(cur ^ 1, (ks + 1) * 32);
            __builtin_amdgcn_sched_barrier(0);
            asm volatile("s_waitcnt vmcnt(7)" ::: "memory");
        } else {
            asm volatile("s_waitcnt vmcnt(0)" ::: "memory");
        }
        __builtin_amdgcn_sched_barrier(0);
        __builtin_amdgcn_s_barrier();

        const char* bb = lds + cur * BUFSZ;
        short8v bh[3], bl[3];
#pragma unroll
        for (int j = 0; j < 3; ++j) {
            int rn = wn * 48 + j * 16 + lr;
            int sn = (lh ^ ((rn >> 1) & 3)) * 16;
            bh[j] = *(const short8v*)(bb + 2 * SEG_A + rn * 64 + sn);
            bl[j] = *(const short8v*)(bb + 2 * SEG_A + SEG_B + rn * 64 + sn);
        }
        __builtin_amdgcn_s_setprio(1);
#pragma unroll
        for (int i = 0; i < 8; ++i) {
            int ra = wm * 128 + i * 16 + lr;
            int sa = (lh ^ ((ra >> 1) & 3)) * 16;
            short8v ah = *(const short8v*)(bb + ra * 64 + sa);
            short8v al = *(const short8v*)(bb + SEG_A + ra * 64 + sa);
#pragma unroll
            for (int j = 0; j < 3; ++j) {
                acc[i][j] = __builtin_amdgcn_mfma_f32_16x16x32_bf16(ah, bh[j], acc[i][j], 0, 0, 0);
                acc[i][j] = __builtin_amdgcn_mfma_f32_16x16x32_bf16(ah, bl[j], acc[i][j], 0, 0, 0);
                acc[i][j] = __builtin_amdgcn_mfma_f32_16x16x32_bf16(al, bh[j], acc[i][j], 0, 0, 0);
            }
        }
        __builtin_amdgcn_s_setprio(0);
        __builtin_amdgcn_sched_barrier(0);
        __builtin_amdgcn_s_barrier();
        cur ^= 1;
    }

    if (MODE == 0) {
#pragma unroll
        for (int i = 0; i < 8; ++i)
#pragma unroll
            for (int j = 0; j < 3; ++j) {
                int n = col0 + wn * 48 + j * 16 + lr;
                float bv = bias[n];
#pragma unroll
                for (int q = 0; q < 4; ++q) {
                    int m = row0 + wm * 128 + i * 16 + lh * 4 + q;
                    float gv = gelu_erf(acc[i][j][q] + bv);
                    short hi = f2bf(gv);
                    short lo = f2bf(gv - bf2f(hi));
                    O_hl[(size_t)m * N + n] =
                        (uint32_t)(uint16_t)hi | ((uint32_t)(uint16_t)lo << 16);
                }
            }
    } else {
        float rs[8][4] = {};
#pragma unroll
        for (int i = 0; i < 8; ++i)
#pragma unroll
            for (int j = 0; j < 3; ++j) {
                int n = col0 + wn * 48 + j * 16 + lr;
                float bv = bias[n], wv = w2[n];
#pragma unroll
                for (int q = 0; q < 4; ++q)
                    rs[i][q] += gelu_erf(acc[i][j][q] + bv) * wv;
            }
#pragma unroll
        for (int i = 0; i < 8; ++i)
#pragma unroll
            for (int q = 0; q < 4; ++q) {
                float vv = rs[i][q];
                vv += __shfl_xor(vv, 1); vv += __shfl_xor(vv, 2);
                vv += __shfl_xor(vv, 4); vv += __shfl_xor(vv, 8);
                if (lr == 0) {
                    int m = chunk_off + row0 + wm * 128 + i * 16 + lh * 4 + q;
                    partials[(size_t)(bx * 4 + wn) * 65536 + m] = vv;
                }
            }
    }
}

// ---------------------------------------------------------------------------
// f32 fallback GEMM for the small qa projection.
constexpr int BKF = 16;
__global__ __launch_bounds__(256)
void rowstats(const float* __restrict__ X, float2* __restrict__ st, int M)
{
    int wave = threadIdx.x >> 6, lane = threadIdx.x & 63;
    int row = blockIdx.x * 4 + wave;
    if (row >= M) return;
    const float4* xr = reinterpret_cast<const float4*>(X + (size_t)row * KDIM);
    float s = 0.f, ss = 0.f;
#pragma unroll
    for (int i = 0; i < 3; ++i) {
        float4 v = xr[lane + i * 64];
        s  += v.x + v.y + v.z + v.w;
        ss += v.x * v.x + v.y * v.y + v.z * v.z + v.w * v.w;
    }
    s = wave_sum(s); ss = wave_sum(ss);
    if (lane == 0) {
        float m = s * (1.0f / 768.0f);
        float var = ss * (1.0f / 768.0f) - m * m;
        float rstd = rsqrtf(var + 1e-5f);
        st[row] = make_float2(rstd, -m * rstd);
    }
}

template<int BM, int BN, int TM, int TN>
__global__ __launch_bounds__(256)
void gemm_fused(const float* __restrict__ X, const float2* __restrict__ st,
                const float* __restrict__ gw, const float* __restrict__ gb,
                const float* __restrict__ W, const float* __restrict__ bias,
                float* __restrict__ out, int M, int N)
{
    static_assert((BM / TM) * (BN / TN) == 256, "256 threads");
    __shared__ float As[BKF][BM];
    __shared__ float Bs[BKF][BN];
    const int t = threadIdx.x;
    constexpr int TXN = BN / TN;
    const int tx = t % TXN;
    const int ty = t / TXN;
    const int row0 = blockIdx.y * BM;
    const int col0 = blockIdx.x * BN;
    float acc[TM][TN] = {};
    constexpr int A_IT = BM * BKF / 4 / 256;
    constexpr int B_IT = BKF * BN / 4 / 256;
    for (int k0 = 0; k0 < KDIM; k0 += BKF) {
#pragma unroll
        for (int i = 0; i < A_IT; ++i) {
            int idx = t + i * 256;
            int r = idx >> 2;
            int c = (idx & 3) << 2;
            float4 xv = *reinterpret_cast<const float4*>(X + (size_t)(row0 + r) * KDIM + k0 + c);
            float2 s = st[row0 + r];
            float4 gv = *reinterpret_cast<const float4*>(gw + k0 + c);
            float4 bv = *reinterpret_cast<const float4*>(gb + k0 + c);
            As[c + 0][r] = fmaf(fmaf(xv.x, s.x, s.y), gv.x, bv.x);
            As[c + 1][r] = fmaf(fmaf(xv.y, s.x, s.y), gv.y, bv.y);
            As[c + 2][r] = fmaf(fmaf(xv.z, s.x, s.y), gv.z, bv.z);
            As[c + 3][r] = fmaf(fmaf(xv.w, s.x, s.y), gv.w, bv.w);
        }
#pragma unroll
        for (int i = 0; i < B_IT; ++i) {
            int idx = t + i * 256;
            int r = idx / (BN / 4);
            int c = (idx % (BN / 4)) << 2;
            *reinterpret_cast<float4*>(&Bs[r][c]) =
                *reinterpret_cast<const float4*>(W + (size_t)(k0 + r) * N + col0 + c);
        }
        __syncthreads();
#pragma unroll
        for (int kk = 0; kk < BKF; ++kk) {
            float a[TM], b[TN];
#pragma unroll
            for (int i = 0; i < TM; i += 4)
                *reinterpret_cast<float4*>(&a[i]) = *reinterpret_cast<const float4*>(&As[kk][ty * TM + i]);
#pragma unroll
            for (int j = 0; j < TN; j += 4)
                *reinterpret_cast<float4*>(&b[j]) = *reinterpret_cast<const float4*>(&Bs[kk][tx * TN + j]);
#pragma unroll
            for (int i = 0; i < TM; ++i)
#pragma unroll
                for (int j = 0; j < TN; ++j)
                    acc[i][j] = fmaf(a[i], b[j], acc[i][j]);
        }
        __syncthreads();
    }
#pragma unroll
    for (int i = 0; i < TM; ++i) {
        size_t row = row0 + ty * TM + i;
#pragma unroll
        for (int j = 0; j < TN; j += 4) {
            int col = col0 + tx * TN + j;
            float4 o;
            o.x = gelu_erf(acc[i][j + 0] + bias[col + 0]);
            o.y = gelu_erf(acc[i][j + 1] + bias[col + 1]);
            o.z = gelu_erf(acc[i][j + 2] + bias[col + 2]);
            o.w = gelu_erf(acc[i][j + 3] + bias[col + 3]);
            *reinterpret_cast<float4*>(out + row * N + col) = o;
        }
    }
}

// ---------------------------------------------------------------------------
// head: logits = sum(8 partials)+b2 -> softmax -> smooth -> softmax -> decode.
__global__ __launch_bounds__(64)
void head_kernel(const float* __restrict__ partials, const float* __restrict__ b2,
                 const float* __restrict__ sigma_p, float* __restrict__ out)
{
    int b = blockIdx.x, lane = threadIdx.x;
    __shared__ float ok[36];
    __shared__ float kg[32];
    __shared__ int sel[2];

    if (lane < 36) ok[lane] = 0.f;
    __syncthreads();

    float x = -3.4e38f;
    if (lane < 32) {
        int row = b * 32 + lane;
        x = b2[0];
#pragma unroll
        for (int p = 0; p < 8; ++p) x += partials[(size_t)p * 65536 + row];
    }
    float mx = wave_max(x);
    float e = (lane < 32) ? expf(x - mx) : 0.f;
    float sum = wave_sum(e);
    float ori = e / sum;
    if (lane < 32) {
        out[OFF_ORI + b * 32 + lane] = ori;
        ok[lane + 2] = ori;
    }
    __syncthreads();

    float sg = sigma_p[0];
    float kern[5]; float ks = 0.f;
#pragma unroll
    for (int k = 0; k < 5; ++k) { float xx = (float)(k - 2) / sg; kern[k] = expf(-0.5f * xx * xx); ks += kern[k]; }
    float sm = -3.4e38f;
    if (lane < 32) {
        sm = 0.f;
#pragma unroll
        for (int k = 0; k < 5; ++k) sm += (kern[k] / ks) * ok[lane + k];
    }
    float mx2 = wave_max(sm);
    float e2 = (lane < 32) ? expf(sm - mx2) : 0.f;
    float sum2 = wave_sum(e2);
    float kgv = e2 / sum2;
    if (lane < 32) {
        out[OFF_KG + b * 32 + lane] = kgv;
        kg[lane] = kgv;
    }
    __syncthreads();

    if (lane == 0) {
        int pm = 0; float bv = kg[0];
        for (int i = 1; i < 32; ++i) if (kg[i] > bv) { bv = kg[i]; pm = i; }
        float cum[33]; cum[0] = 0.f;
        for (int i = 0; i < 32; ++i) cum[i + 1] = cum[i] + kg[i];
        float bs = -3.4e38f; int bst = 0, ben = 0;
        const int wsz[3] = {1, 3, 5};
        for (int wi = 0; wi < 3; ++wi) {
            int w = wsz[wi];
            for (int s = 0; s + w <= 32; ++s) {
                if (pm >= s && pm < s + w) {
                    float sc = cum[s + w] - cum[s];
                    if (sc > bs) { bs = sc; bst = s; ben = s + w; }
                }
            }
        }
        out[OFF_MI + b * 2 + 0] = (float)bst;
        out[OFF_MI + b * 2 + 1] = (float)ben;
        out[OFF_ST + b] = (float)bst / 31.0f;
        out[OFF_ET + b] = (float)ben / 31.0f;
        sel[0] = bst; sel[1] = ben;
    }
    __syncthreads();
    if (lane < 32)
        out[OFF_MASK + b * 32 + lane] = (lane >= sel[0] && lane <= sel[1]) ? 1.0f : 0.0f;
}

// ---------------------------------------------------------------------------
extern "C" void kernel_launch(void* const* d_in, const int* in_sizes, int n_in,
                              void* d_out, int out_size, void* d_ws, size_t ws_size,
                              hipStream_t stream)
{
    const float* v      = (const float*)d_in[0];
    const float* qa     = (const float*)d_in[1];
    const float* vp_lng = (const float*)d_in[2];
    const float* vp_lnb = (const float*)d_in[3];
    const float* vp_w   = (const float*)d_in[4];
    const float* vp_b   = (const float*)d_in[5];
    const float* qp_lng = (const float*)d_in[6];
    const float* qp_lnb = (const float*)d_in[7];
    const float* qp_w   = (const float*)d_in[8];
    const float* qp_b   = (const float*)d_in[9];
    const float* g_lng  = (const float*)d_in[10];
    const float* g_lnb  = (const float*)d_in[11];
    const float* g_w1   = (const float*)d_in[12];
    const float* g_b1   = (const float*)d_in[13];
    const float* g_w2   = (const float*)d_in[14];
    const float* g_b2   = (const float*)d_in[15];
    const float* sigma  = (const float*)d_in[16];
    float* outf = (float*)d_out;

    // workspace layout (~213 MB)
    short* A1h = (short*)d_ws;                           // CHUNK*768
    short* A1l = A1h + (size_t)CHUNK * KDIM;
    uint32_t* vp_hl = (uint32_t*)(A1l + (size_t)CHUNK * KDIM);   // CHUNK*768 u32
    short* B1h = (short*)(vp_hl + (size_t)CHUNK * KDIM); // 768*768
    short* B1l = B1h + 768 * KDIM;
    short* B2h = B1l + 768 * KDIM;                       // 384*768
    short* B2l = B2h + 384 * KDIM;
    float* qa_p = (float*)(B2l + 384 * KDIM);            // 2048*768
    float* st_qa = qa_p + 2048 * KDIM;                   // 2048*2
    float* partials = st_qa + 4096;                      // 8*65536

    // qa path (small, f32 vector GEMM)
    rowstats<<<512, 256, 0, stream>>>(qa, (float2*)st_qa, 2048);
    gemm_fused<64, 64, 4, 4><<<dim3(12, 32), 256, 0, stream>>>(
        qa, (const float2*)st_qa, qp_lng, qp_lnb, qp_w, qp_b, qa_p, 2048, 768);

    // weight transpose + split
    prep_W<<<dim3(24, 24), 256, 0, stream>>>(vp_w, B1h, B1l, 768);
    prep_W<<<dim3(12, 24), 256, 0, stream>>>(g_w1, B2h, B2l, 384);

    constexpr int LDSB = 2 * (2 * 256 * 64 + 2 * 192 * 64);   // 114688

    for (int c = 0; c < 65536; c += CHUNK) {
        prep_A1<<<CHUNK / 4, 256, 0, stream>>>(v + (size_t)c * KDIM, vp_lng, vp_lnb, A1h, A1l);
        // v_p = gelu(A1 @ vp_w^T + vp_b): grid (4,128) = 512 blocks, 2 full waves
        gemm_mfma<0><<<dim3(4, CHUNK / 256), 512, LDSB, stream>>>(
            A1h, A1l, B1h, B1l, vp_b, vp_hl, 768, nullptr, nullptr, 0);
        prep_A2<<<CHUNK / 4, 256, 0, stream>>>(vp_hl, qa_p, g_lng, g_lnb, A1h, A1l, c);
        // fused h@g_w1+gelu+dot(g_w2): grid (2,128) = 256 blocks
        gemm_mfma<1><<<dim3(2, CHUNK / 256), 512, LDSB, stream>>>(
            A1h, A1l, B2h, B2l, g_b1, nullptr, 384, g_w2, partials, c);
    }

    head_kernel<<<2048, 64, 0, stream>>>(partials, g_b2, sigma, outf);
}